// Round 2
// baseline (729.116 us; speedup 1.0000x reference)
//
#include <hip/hip_runtime.h>

// weighted_loss: graph-weighted cross entropy
//   p[i] packs deg (low16) and s0 (high16); s1 = deg - s0
//   cnt[i] = #nodes sharing key (x[i], s0[i], s1[i]) ; w = cnt^-0.5
//   out = sum(w * nll) / sum(w),  nll = -log_softmax(out)[i, y[i]]

#define KDIM 256                 // max degree per coordinate; deg ~ Poisson(64)
#define HIST_BINS (2 * KDIM * KDIM)

// ---------------- kernel 1: edge scatter-count ----------------
// One packed atomic per edge: p[row] += 1 | ((x[col]>0) << 16).
// Unrolled 16 edges/iter: all loads, then all gathers, then all atomics,
// so each in-order vmcnt drain retires 16 atomics instead of 4.
__global__ __launch_bounds__(256) void edge_count_kernel(
    const int* __restrict__ row, const int* __restrict__ col,
    const int* __restrict__ x, unsigned int* __restrict__ p, int E)
{
    int tid = blockIdx.x * blockDim.x + threadIdx.x;
    int stride = gridDim.x * blockDim.x;
    int E4 = E >> 2;
    const int4* row4 = (const int4*)row;
    const int4* col4 = (const int4*)col;

    int i = tid;
    for (; i + 3 * stride < E4; i += 4 * stride) {
        int4 c0 = col4[i];
        int4 c1 = col4[i + stride];
        int4 c2 = col4[i + 2 * stride];
        int4 c3 = col4[i + 3 * stride];
        int4 r0 = row4[i];
        int4 r1 = row4[i + stride];
        int4 r2 = row4[i + 2 * stride];
        int4 r3 = row4[i + 3 * stride];
        unsigned int a00 = (x[c0.x] > 0) ? 0x10001u : 1u;
        unsigned int a01 = (x[c0.y] > 0) ? 0x10001u : 1u;
        unsigned int a02 = (x[c0.z] > 0) ? 0x10001u : 1u;
        unsigned int a03 = (x[c0.w] > 0) ? 0x10001u : 1u;
        unsigned int a10 = (x[c1.x] > 0) ? 0x10001u : 1u;
        unsigned int a11 = (x[c1.y] > 0) ? 0x10001u : 1u;
        unsigned int a12 = (x[c1.z] > 0) ? 0x10001u : 1u;
        unsigned int a13 = (x[c1.w] > 0) ? 0x10001u : 1u;
        unsigned int a20 = (x[c2.x] > 0) ? 0x10001u : 1u;
        unsigned int a21 = (x[c2.y] > 0) ? 0x10001u : 1u;
        unsigned int a22 = (x[c2.z] > 0) ? 0x10001u : 1u;
        unsigned int a23 = (x[c2.w] > 0) ? 0x10001u : 1u;
        unsigned int a30 = (x[c3.x] > 0) ? 0x10001u : 1u;
        unsigned int a31 = (x[c3.y] > 0) ? 0x10001u : 1u;
        unsigned int a32 = (x[c3.z] > 0) ? 0x10001u : 1u;
        unsigned int a33 = (x[c3.w] > 0) ? 0x10001u : 1u;
        atomicAdd(&p[r0.x], a00);
        atomicAdd(&p[r0.y], a01);
        atomicAdd(&p[r0.z], a02);
        atomicAdd(&p[r0.w], a03);
        atomicAdd(&p[r1.x], a10);
        atomicAdd(&p[r1.y], a11);
        atomicAdd(&p[r1.z], a12);
        atomicAdd(&p[r1.w], a13);
        atomicAdd(&p[r2.x], a20);
        atomicAdd(&p[r2.y], a21);
        atomicAdd(&p[r2.z], a22);
        atomicAdd(&p[r2.w], a23);
        atomicAdd(&p[r3.x], a30);
        atomicAdd(&p[r3.y], a31);
        atomicAdd(&p[r3.z], a32);
        atomicAdd(&p[r3.w], a33);
    }
    for (; i < E4; i += stride) {
        int4 c = col4[i];
        int4 r = row4[i];
        atomicAdd(&p[r.x], (x[c.x] > 0) ? 0x10001u : 1u);
        atomicAdd(&p[r.y], (x[c.y] > 0) ? 0x10001u : 1u);
        atomicAdd(&p[r.z], (x[c.z] > 0) ? 0x10001u : 1u);
        atomicAdd(&p[r.w], (x[c.w] > 0) ? 0x10001u : 1u);
    }
    for (int e = (E4 << 2) + tid; e < E; e += stride) {
        atomicAdd(&p[row[e]], (x[col[e]] > 0) ? 0x10001u : 1u);
    }
}

// ---------------- kernel 2: key histogram ----------------
__global__ void hist_kernel(const int* __restrict__ x,
                            const unsigned int* __restrict__ p,
                            int* __restrict__ hist, int N)
{
    int i = blockIdx.x * blockDim.x + threadIdx.x;
    if (i < N) {
        unsigned int pi = p[i];
        int s0 = (int)(pi >> 16);
        int s1 = (int)(pi & 0xFFFFu) - s0;
        s0 = min(s0, KDIM - 1);
        s1 = min(s1, KDIM - 1);
        int key = ((x[i] > 0) ? KDIM * KDIM : 0) + s0 * KDIM + s1;
        atomicAdd(&hist[key], 1);
    }
}

// ---------------- kernel 3: weighted NLL + reduction ----------------
__global__ void loss_kernel(const float* __restrict__ outp,
                            const int* __restrict__ x,
                            const int* __restrict__ y,
                            const unsigned int* __restrict__ p,
                            const int* __restrict__ hist,
                            double* __restrict__ acc,   // acc[0]=sum(w*nll), acc[1]=sum(w)
                            int N)
{
    int tid = blockIdx.x * blockDim.x + threadIdx.x;
    int stride = gridDim.x * blockDim.x;
    double wn = 0.0, wsum = 0.0;
    const float2* out2 = (const float2*)outp;
    for (int i = tid; i < N; i += stride) {
        unsigned int pi = p[i];
        int s0 = (int)(pi >> 16);
        int s1 = (int)(pi & 0xFFFFu) - s0;
        s0 = min(s0, KDIM - 1);
        s1 = min(s1, KDIM - 1);
        int key = ((x[i] > 0) ? KDIM * KDIM : 0) + s0 * KDIM + s1;
        int cnt = hist[key];
        float w = 1.0f / sqrtf((float)cnt);   // cnt >= 1 (node itself)
        float2 o = out2[i];
        float m = fmaxf(o.x, o.y);
        float lse = m + logf(expf(o.x - m) + expf(o.y - m));
        float oy = (y[i] == 0) ? o.x : o.y;
        float nll = lse - oy;
        wn += (double)(w * nll);
        wsum += (double)w;
    }
    for (int off = 32; off > 0; off >>= 1) {
        wn += __shfl_down(wn, off);
        wsum += __shfl_down(wsum, off);
    }
    if ((threadIdx.x & 63) == 0) {
        atomicAdd(&acc[0], wn);
        atomicAdd(&acc[1], wsum);
    }
}

// ---------------- kernel 4: finalize ----------------
__global__ void final_kernel(const double* __restrict__ acc, float* __restrict__ out) {
    out[0] = (float)(acc[0] / acc[1]);
}

extern "C" void kernel_launch(void* const* d_in, const int* in_sizes, int n_in,
                              void* d_out, int out_size, void* d_ws, size_t ws_size,
                              hipStream_t stream) {
    const float* outp = (const float*)d_in[0];   // (N,2) fp32
    const int*   x    = (const int*)d_in[1];     // (N,)
    const int*   y    = (const int*)d_in[2];     // (N,)
    const int*   ei   = (const int*)d_in[3];     // (2,E)
    int N = in_sizes[1];
    int E = in_sizes[3] / 2;
    const int* row = ei;
    const int* col = ei + E;

    // workspace: [acc: 2 doubles][p: N u32][hist: HIST_BINS ints]
    char* ws = (char*)d_ws;
    double* acc = (double*)ws;
    unsigned int* p = (unsigned int*)(ws + 256);
    size_t pBytes = (size_t)N * sizeof(unsigned int);
    size_t histOff = 256 + ((pBytes + 255) & ~(size_t)255);
    int* hist = (int*)(ws + histOff);
    size_t totalWs = histOff + (size_t)HIST_BINS * sizeof(int);

    hipMemsetAsync(d_ws, 0, totalWs, stream);

    const int threads = 256;
    // 1536 blocks = 6 blocks/CU resident (24 waves/CU), each thread runs the
    // 16-edge unrolled body ~2x. More blocks -> too few iterations per thread;
    // fewer -> too few waves for atomic-latency hiding.
    int eblocks = 1536;
    edge_count_kernel<<<eblocks, threads, 0, stream>>>(row, col, x, p, E);

    int nblocks = (N + threads - 1) / threads;
    hist_kernel<<<nblocks, threads, 0, stream>>>(x, p, hist, N);
    loss_kernel<<<nblocks, threads, 0, stream>>>(outp, x, y, p, hist, acc, N);
    final_kernel<<<1, 1, 0, stream>>>(acc, (float*)d_out);
}